// Round 3
// baseline (861.321 us; speedup 1.0000x reference)
//
#include <hip/hip_runtime.h>

// Head: out = dropout(Q K^T * 1/8, p=0.2) V, no softmax.
// B=4 T=4096 E=1024 H=64. fp32 in/out.
// Round 2: dropout mask = JAX partitionable threefry:
//   bits[j] = o0 ^ o1 of threefry2x32(key=(0,42), ctr=(0, j))   <-- XOR fix
// (hash core verified against Random123 KAT by hand; round-1 used o1 only.)

#define TB 4
#define TT 4096
#define TE 1024
#define TH 64

#define TQB 16   // q rows per block (attention)
#define TKB 64   // keys per tile step

// combined scale: (1/sqrt(64)) * (1/(1-0.2)) = 0.125 * 1.25
#define COMB_SCALE 0.15625f

__device__ __forceinline__ unsigned rotl32(unsigned x, int d) {
  return (x << d) | (x >> (32 - d));
}

// Exact JAX threefry2x32 with key (0, 42)  [jax.random.key(42)]
// Verified against Random123 KAT: key=(0,0), ctr=(0,0) -> (6b200159, 99ba4efe).
__device__ __forceinline__ void threefry2x32_42(unsigned x0, unsigned x1,
                                                unsigned& o0, unsigned& o1) {
  const unsigned ks0 = 0u;
  const unsigned ks1 = 42u;
  const unsigned ks2 = 0x1BD11BDAu ^ 0u ^ 42u;
  x0 += ks0; x1 += ks1;
#define TF_RND(d) { x0 += x1; x1 = rotl32(x1, (d)); x1 ^= x0; }
  TF_RND(13) TF_RND(15) TF_RND(26) TF_RND(6)
  x0 += ks1; x1 += ks2 + 1u;
  TF_RND(17) TF_RND(29) TF_RND(16) TF_RND(24)
  x0 += ks2; x1 += ks0 + 2u;
  TF_RND(13) TF_RND(15) TF_RND(26) TF_RND(6)
  x0 += ks0; x1 += ks1 + 3u;
  TF_RND(17) TF_RND(29) TF_RND(16) TF_RND(24)
  x0 += ks1; x1 += ks2 + 4u;
  TF_RND(13) TF_RND(15) TF_RND(26) TF_RND(6)
  x0 += ks2; x1 += ks0 + 5u;
#undef TF_RND
  o0 = x0; o1 = x1;
}

// keep decision for flat index j, JAX partitionable scheme (default >=0.4.36):
//   x1,x2 = iota_2x32_shape = (0, j) for j < 2^32
//   bits1, bits2 = threefry2x32(key, x1, x2)
//   bits(32) = bits1 ^ bits2            <-- uses BOTH output words
//   uniform = bitcast(bits>>9 | 0x3f800000) - 1 ;  keep = u < 0.8f
__device__ __forceinline__ bool keep_mask(unsigned j) {
  unsigned o0, o1;
  threefry2x32_42(0u, j, o0, o1);
  unsigned bits = o0 ^ o1;
  float u = __uint_as_float((bits >> 9) | 0x3f800000u) - 1.0f;
  return u < 0.8f;
}

// ---------------------------------------------------------------------------
// Projection: q = x Wq, k = x Wk, v = x Wv.
// q_out, v_out: [B][T][H] row-major. kT_out: [B][H][T] (transposed, so the
// attention kernel can stage K^T tiles with coalesced reads + conflict-free
// LDS writes).
// Block: 256 thr = 4 row-groups x 64 h; each thread 4 rows; block = 16 rows.
// ---------------------------------------------------------------------------
__global__ __launch_bounds__(256)
void proj_kernel(const float* __restrict__ x,
                 const float* __restrict__ Wk,
                 const float* __restrict__ Wq,
                 const float* __restrict__ Wv,
                 float* __restrict__ q_out,
                 float* __restrict__ kT_out,
                 float* __restrict__ v_out)
{
  __shared__ float kbuf[16][TH + 1];  // +1 pad: transposed readback
  const int tid = threadIdx.x;
  const int h  = tid & 63;
  const int rg = tid >> 6;                 // 0..3
  const int row_base = blockIdx.x * 16;    // global row = b*T + t
  const int r0 = row_base + rg * 4;

  float ak[4] = {0.f, 0.f, 0.f, 0.f};
  float aq[4] = {0.f, 0.f, 0.f, 0.f};
  float av[4] = {0.f, 0.f, 0.f, 0.f};

  const float* xr = x + (size_t)r0 * TE;
  for (int e4 = 0; e4 < TE / 4; ++e4) {
    float4 xv[4];
#pragma unroll
    for (int r = 0; r < 4; ++r)
      xv[r] = reinterpret_cast<const float4*>(xr + (size_t)r * TE)[e4];
#pragma unroll
    for (int j = 0; j < 4; ++j) {
      const int e = e4 * 4 + j;
      const float wk = Wk[e * TH + h];
      const float wq = Wq[e * TH + h];
      const float wv = Wv[e * TH + h];
#pragma unroll
      for (int r = 0; r < 4; ++r) {
        const float xs = (&xv[r].x)[j];
        ak[r] += xs * wk;
        aq[r] += xs * wq;
        av[r] += xs * wv;
      }
    }
  }

#pragma unroll
  for (int r = 0; r < 4; ++r) {
    const int row = r0 + r;
    q_out[(size_t)row * TH + h] = aq[r];
    v_out[(size_t)row * TH + h] = av[r];
    kbuf[rg * 4 + r][h] = ak[r];
  }
  __syncthreads();
  // transpose-write K: kT[(b*H + h2)*T + t], 16 t's per h2, float4 chunks
  {
    const int b  = row_base >> 12;          // /T
    const int t0 = row_base & (TT - 1);
    const int h2 = tid >> 2;                // 0..63
    const int c  = tid & 3;                 // t sub-chunk
    float4 vv;
    vv.x = kbuf[c * 4 + 0][h2];
    vv.y = kbuf[c * 4 + 1][h2];
    vv.z = kbuf[c * 4 + 2][h2];
    vv.w = kbuf[c * 4 + 3][h2];
    *reinterpret_cast<float4*>(
        kT_out + ((size_t)(b * TH + h2) * TT + t0 + c * 4)) = vv;
  }
}

// ---------------------------------------------------------------------------
// Fused attention (no softmax): per (b, 16-row q tile), loop over 64-key
// tiles: S = Q K^T, dropout+scale, O += S V.  All fp32.
// Phase1 ownership: thread = (row 0..15, colgroup 0..15) -> 4 S cols.
// Phase2 ownership: thread = (rowgroup 0..3, h 0..63)   -> 4 O rows.
// ---------------------------------------------------------------------------
__global__ __launch_bounds__(256)
void attn_kernel(const float* __restrict__ q_in,   // [B][T][H]
                 const float* __restrict__ kT_in,  // [B][H][T]
                 const float* __restrict__ v_in,   // [B][T][H]
                 float* __restrict__ out)          // [B][T][H]
{
  __shared__ float Qs[TQB][TH + 1];  // pad: 4 distinct rows/wave in phase1
  __shared__ float Kt[TH][TKB];      // [h][k], unpadded: aligned float4 reads
  __shared__ float Sv[TQB][TKB];     // unpadded: wave-uniform float4 bcast
  __shared__ float Vs[TKB][TH];      // [k][h]

  const int tid = threadIdx.x;
  const int b  = blockIdx.x >> 8;    // 256 q-tiles per batch
  const int qt = blockIdx.x & 255;

  const int lane_h = tid & 63;
  const int rg     = tid >> 6;       // 0..3
  const int p1_row = tid >> 4;       // 0..15
  const int p1_cg  = tid & 15;       // 0..15 -> cols 4cg..4cg+3

  const float* qb  = q_in  + ((size_t)b * TT + qt * TQB) * TH;
  const float* kTb = kT_in + (size_t)b * TH * TT;
  const float* vb  = v_in  + (size_t)b * TT * TH;

  for (int i = tid; i < TQB * TH; i += 256)
    Qs[i >> 6][i & 63] = qb[i];

  float acc0 = 0.f, acc1 = 0.f, acc2 = 0.f, acc3 = 0.f;

  const unsigned qrow_base = (unsigned)(b * TT + qt * TQB);

  for (int kt = 0; kt < TT / TKB; ++kt) {
    const int k0 = kt * TKB;
    __syncthreads();  // prev phase2 done (also covers initial Q load)

    // stage K^T tile and V tile (coalesced reads, conflict-free LDS writes)
#pragma unroll 4
    for (int ii = 0; ii < 16; ++ii) {
      const int i = rg * 16 + ii;
      Kt[i][lane_h] = kTb[(size_t)i * TT + k0 + lane_h];
      Vs[i][lane_h] = vb[(size_t)(k0 + i) * TH + lane_h];
    }
    __syncthreads();

    // phase 1: S[row][4cg+c] = sum_h Q[row][h] * K[k0+4cg+c][h]
    float s0 = 0.f, s1 = 0.f, s2 = 0.f, s3 = 0.f;
    {
      const float4* Kt4 = reinterpret_cast<const float4*>(&Kt[0][0]);
      for (int hh = 0; hh < TH; ++hh) {
        const float qv = Qs[p1_row][hh];
        const float4 kv = Kt4[hh * 16 + p1_cg];
        s0 += qv * kv.x; s1 += qv * kv.y; s2 += qv * kv.z; s3 += qv * kv.w;
      }
    }

    // dropout + combined scale; write S tile
    {
      const unsigned q = qrow_base + (unsigned)p1_row;
      const unsigned jb = q * (unsigned)TT + (unsigned)(k0 + p1_cg * 4);
      float4 sw;
      float sv[4] = {s0, s1, s2, s3};
#pragma unroll
      for (int c = 0; c < 4; ++c)
        (&sw.x)[c] = keep_mask(jb + (unsigned)c) ? sv[c] * COMB_SCALE : 0.f;
      reinterpret_cast<float4*>(&Sv[0][0])[p1_row * 16 + p1_cg] = sw;
    }
    __syncthreads();

    // phase 2: O[rg*4+r][h] += sum_k S[.][k] * V[k][h]
    {
      const float4* Sv4 = reinterpret_cast<const float4*>(&Sv[0][0]);
      const int r0 = rg * 4;
#pragma unroll 4
      for (int kc = 0; kc < 16; ++kc) {
        const float4 sa = Sv4[(r0 + 0) * 16 + kc];
        const float4 sb = Sv4[(r0 + 1) * 16 + kc];
        const float4 sc = Sv4[(r0 + 2) * 16 + kc];
        const float4 sd = Sv4[(r0 + 3) * 16 + kc];
        const float v0 = Vs[kc * 4 + 0][lane_h];
        const float v1 = Vs[kc * 4 + 1][lane_h];
        const float v2 = Vs[kc * 4 + 2][lane_h];
        const float v3 = Vs[kc * 4 + 3][lane_h];
        acc0 += sa.x * v0 + sa.y * v1 + sa.z * v2 + sa.w * v3;
        acc1 += sb.x * v0 + sb.y * v1 + sb.z * v2 + sb.w * v3;
        acc2 += sc.x * v0 + sc.y * v1 + sc.z * v2 + sc.w * v3;
        acc3 += sd.x * v0 + sd.y * v1 + sd.z * v2 + sd.w * v3;
      }
    }
  }

  {
    const size_t ob = ((size_t)b * TT + (size_t)qt * TQB + rg * 4) * TH + lane_h;
    out[ob + 0 * TH] = acc0;
    out[ob + 1 * TH] = acc1;
    out[ob + 2 * TH] = acc2;
    out[ob + 3 * TH] = acc3;
  }
}

extern "C" void kernel_launch(void* const* d_in, const int* in_sizes, int n_in,
                              void* d_out, int out_size, void* d_ws, size_t ws_size,
                              hipStream_t stream) {
  const float* x  = (const float*)d_in[0];
  const float* Wk = (const float*)d_in[1];
  const float* Wq = (const float*)d_in[2];
  const float* Wv = (const float*)d_in[3];
  float* outp = (float*)d_out;

  const size_t SZ = (size_t)TB * TT * TH;  // 1,048,576 floats each
  float* q_ws  = (float*)d_ws;
  float* kT_ws = q_ws + SZ;
  float* v_ws  = kT_ws + SZ;
  // ws use: 12 MB total

  proj_kernel<<<dim3(TB * TT / 16), dim3(256), 0, stream>>>(
      x, Wk, Wq, Wv, q_ws, kT_ws, v_ws);
  attn_kernel<<<dim3(TB * (TT / TQB)), dim3(256), 0, stream>>>(
      q_ws, kT_ws, v_ws, outp);
}

// Round 4
// 400.895 us; speedup vs baseline: 2.1485x; 2.1485x over previous
//
#include <hip/hip_runtime.h>

// Head: out = dropout(Q K^T / 8, p=0.2) V  (no softmax). B=4 T=4096 E=1024 H=64.
// Round 3: attention on bf16 MFMA (16x16x32), threefry mask on VALU,
// barrier-free k-loop, wave-private swizzled S staging in LDS.
// Proj still fp32 VALU but emits bf16 Q(pre-scaled)/K/V^T.

#define TB 4
#define TT 4096
#define TE 1024
#define TH 64
#define COMB_SCALE 0.15625f   // 0.125 * 1.25 folded into Q

typedef __bf16 bf16x8 __attribute__((ext_vector_type(8)));
typedef __bf16 bf16x4 __attribute__((ext_vector_type(4)));
typedef float  f32x4  __attribute__((ext_vector_type(4)));

__device__ __forceinline__ unsigned rotl32(unsigned x, int d) {
  return (x << d) | (x >> (32 - d));
}

// Exact JAX threefry2x32, key (0,42); returns o0 ^ o1 (partitionable scheme).
__device__ __forceinline__ unsigned tf_bits(unsigned j) {
  const unsigned ks1 = 42u;
  const unsigned ks2 = 0x1BD11BDAu ^ 42u;
  unsigned x0 = 0u, x1 = j + ks1;
#define TF_RND(d) { x0 += x1; x1 = rotl32(x1, (d)); x1 ^= x0; }
  TF_RND(13) TF_RND(15) TF_RND(26) TF_RND(6)
  x0 += ks1; x1 += ks2 + 1u;
  TF_RND(17) TF_RND(29) TF_RND(16) TF_RND(24)
  x0 += ks2; x1 += 0u + 2u;
  TF_RND(13) TF_RND(15) TF_RND(26) TF_RND(6)
  x0 += 0u;  x1 += ks1 + 3u;
  TF_RND(17) TF_RND(29) TF_RND(16) TF_RND(24)
  x0 += ks1; x1 += ks2 + 4u;
  TF_RND(13) TF_RND(15) TF_RND(26) TF_RND(6)
  x0 += ks2; x1 += 0u + 5u;
#undef TF_RND
  return x0 ^ x1;
}

// keep  <=>  uniform(bits) < 0.8f  <=>  (bits>>9) < 6710887   (exact: see notes)
__device__ __forceinline__ bool tf_keep(unsigned j) {
  return (tf_bits(j) >> 9) < 6710887u;
}

// ---------------------------------------------------------------------------
// Projection (fp32 VALU, bf16 outputs): qs=[B][T][H] (pre-scaled), ks=[B][T][H],
// vT=[B][H][T].
// ---------------------------------------------------------------------------
__global__ __launch_bounds__(256)
void proj_kernel(const float* __restrict__ x,
                 const float* __restrict__ Wk,
                 const float* __restrict__ Wq,
                 const float* __restrict__ Wv,
                 __bf16* __restrict__ qs,
                 __bf16* __restrict__ ks,
                 __bf16* __restrict__ vT)
{
  __shared__ float vbuf[16][TH + 1];
  const int tid = threadIdx.x;
  const int h  = tid & 63;
  const int rg = tid >> 6;
  const int row_base = blockIdx.x * 16;
  const int r0 = row_base + rg * 4;

  float ak[4] = {0.f,0.f,0.f,0.f};
  float aq[4] = {0.f,0.f,0.f,0.f};
  float av[4] = {0.f,0.f,0.f,0.f};

  const float* xr = x + (size_t)r0 * TE;
  for (int e4 = 0; e4 < TE / 4; ++e4) {
    float4 xv[4];
#pragma unroll
    for (int r = 0; r < 4; ++r)
      xv[r] = reinterpret_cast<const float4*>(xr + (size_t)r * TE)[e4];
#pragma unroll
    for (int j = 0; j < 4; ++j) {
      const int e = e4 * 4 + j;
      const float wk = Wk[e * TH + h];
      const float wq = Wq[e * TH + h];
      const float wv = Wv[e * TH + h];
#pragma unroll
      for (int r = 0; r < 4; ++r) {
        const float xs = (&xv[r].x)[j];
        ak[r] += xs * wk;
        aq[r] += xs * wq;
        av[r] += xs * wv;
      }
    }
  }

#pragma unroll
  for (int r = 0; r < 4; ++r) {
    const int row = r0 + r;
    qs[(size_t)row * TH + h] = (__bf16)(aq[r] * COMB_SCALE);
    ks[(size_t)row * TH + h] = (__bf16)ak[r];
    vbuf[rg * 4 + r][h] = av[r];
  }
  __syncthreads();
  {
    const int b  = row_base >> 12;
    const int t0 = row_base & (TT - 1);
    const int h2 = tid >> 2;
    const int c  = tid & 3;
    bf16x4 vv;
#pragma unroll
    for (int i = 0; i < 4; ++i) vv[i] = (__bf16)vbuf[c * 4 + i][h2];
    *reinterpret_cast<bf16x4*>(vT + ((size_t)(b * TH + h2) * TT + t0 + c * 4)) = vv;
  }
}

// ---------------------------------------------------------------------------
// Attention, MFMA. Grid 512: block -> (b, 32 q-rows). 4 waves: wave w owns
// q-16-tile (w&1) and KV half (w>>1). Barrier-free k-loop; one final barrier
// for the KV-half reduction.
// ---------------------------------------------------------------------------
__global__ __launch_bounds__(256)
void attn_mfma(const __bf16* __restrict__ qs,
               const __bf16* __restrict__ ks,
               const __bf16* __restrict__ vT,
               float* __restrict__ out)
{
  __shared__ __bf16 S_lds[4][16 * 64];   // wave-private, XOR-swizzled
  __shared__ float  Oex[2][16][TH + 1];  // KV-half exchange

  const int tid = threadIdx.x;
  const int w   = tid >> 6;
  const int l   = tid & 63;
  const int l4  = l >> 4;     // 0..3
  const int lm  = l & 15;     // 0..15

  const int b    = blockIdx.x >> 7;
  const int qt32 = blockIdx.x & 127;
  const int qt16 = qt32 * 2 + (w & 1);
  const int kv0  = (w >> 1) * (TT / 2);
  const int qrow0 = qt16 * 16;

  // Q A-frags: lane holds Q[row=lm][h=l4*8 .. +7] (+32 for the second half)
  const __bf16* qb = qs + ((size_t)b * TT + qrow0) * TH;
  const bf16x8 qf0 = *reinterpret_cast<const bf16x8*>(qb + (size_t)lm * TH + l4 * 8);
  const bf16x8 qf1 = *reinterpret_cast<const bf16x8*>(qb + (size_t)lm * TH + 32 + l4 * 8);

  const __bf16* kbp = ks + (size_t)b * TT * TH;
  const __bf16* vbp = vT + (size_t)b * TH * TT;

  f32x4 o_acc[4] = {{0.f,0.f,0.f,0.f},{0.f,0.f,0.f,0.f},
                    {0.f,0.f,0.f,0.f},{0.f,0.f,0.f,0.f}};

  const unsigned base0 = ((unsigned)(b * TT) + (unsigned)qrow0 + (unsigned)(l4 * 4)) * (unsigned)TT;
  const unsigned sw = (unsigned)((lm & 7) << 3);  // A-row swizzle for this lane

  for (int kb = kv0; kb < kv0 + TT / 2; kb += 64) {
    // ---- load K/V B-frags straight from global (L2-resident) ----
    bf16x8 kf[4][2], vf[4][2];
#pragma unroll
    for (int t = 0; t < 4; ++t) {
      const __bf16* kr = kbp + (size_t)(kb + t * 16 + lm) * TH;
#pragma unroll
      for (int s = 0; s < 2; ++s)
        kf[t][s] = *reinterpret_cast<const bf16x8*>(kr + s * 32 + l4 * 8);
    }
#pragma unroll
    for (int t = 0; t < 4; ++t) {
      const __bf16* vr = vbp + (size_t)(t * 16 + lm) * TT + kb;
#pragma unroll
      for (int s = 0; s < 2; ++s)
        vf[t][s] = *reinterpret_cast<const bf16x8*>(vr + s * 32 + l4 * 8);
    }

    // ---- S = Q K^T (scaled via pre-scaled Q) ----
    f32x4 sa[4];
#pragma unroll
    for (int t = 0; t < 4; ++t) {
      f32x4 c = {0.f, 0.f, 0.f, 0.f};
      c = __builtin_amdgcn_mfma_f32_16x16x32_bf16(qf0, kf[t][0], c, 0, 0, 0);
      c = __builtin_amdgcn_mfma_f32_16x16x32_bf16(qf1, kf[t][1], c, 0, 0, 0);
      sa[t] = c;
    }

    // ---- dropout mask (threefry, exact) + bf16 + swizzled S store ----
    const unsigned jcol = (unsigned)kb + (unsigned)lm;
#pragma unroll
    for (int t = 0; t < 4; ++t) {
#pragma unroll
      for (int r = 0; r < 4; ++r) {
        const unsigned j = base0 + (unsigned)(r * TT) + jcol + (unsigned)(t * 16);
        const float svv = tf_keep(j) ? sa[t][r] : 0.0f;
        const int row = l4 * 4 + r;
        const int col = t * 16 + lm;
        S_lds[w][row * 64 + (col ^ ((row & 7) << 3))] = (__bf16)svv;
      }
    }

    // ---- reload S as PV A-frags (same-wave dep; compiler inserts lgkmcnt) ----
    const bf16x8 af0 = *reinterpret_cast<const bf16x8*>(
        &S_lds[w][lm * 64 + ((unsigned)(l4 * 8) ^ sw)]);
    const bf16x8 af1 = *reinterpret_cast<const bf16x8*>(
        &S_lds[w][lm * 64 + ((unsigned)(32 + l4 * 8) ^ sw)]);

    // ---- O += S V ----
#pragma unroll
    for (int t = 0; t < 4; ++t) {
      o_acc[t] = __builtin_amdgcn_mfma_f32_16x16x32_bf16(af0, vf[t][0], o_acc[t], 0, 0, 0);
      o_acc[t] = __builtin_amdgcn_mfma_f32_16x16x32_bf16(af1, vf[t][1], o_acc[t], 0, 0, 0);
    }
  }

  // ---- combine KV halves: waves 2,3 hand off to waves 0,1 ----
  if (w >= 2) {
#pragma unroll
    for (int t = 0; t < 4; ++t)
#pragma unroll
      for (int r = 0; r < 4; ++r)
        Oex[w - 2][l4 * 4 + r][t * 16 + lm] = o_acc[t][r];
  }
  __syncthreads();
  if (w < 2) {
    float* outb = out + ((size_t)b * TT + qrow0) * TH;
#pragma unroll
    for (int t = 0; t < 4; ++t)
#pragma unroll
      for (int r = 0; r < 4; ++r) {
        const float v = o_acc[t][r] + Oex[w][l4 * 4 + r][t * 16 + lm];
        outb[(size_t)(l4 * 4 + r) * TH + t * 16 + lm] = v;
      }
  }
}

extern "C" void kernel_launch(void* const* d_in, const int* in_sizes, int n_in,
                              void* d_out, int out_size, void* d_ws, size_t ws_size,
                              hipStream_t stream) {
  const float* x  = (const float*)d_in[0];
  const float* Wk = (const float*)d_in[1];
  const float* Wq = (const float*)d_in[2];
  const float* Wv = (const float*)d_in[3];
  float* outp = (float*)d_out;

  const size_t SZ = (size_t)TB * TT * TH;  // 1,048,576 elements each
  __bf16* q_ws  = (__bf16*)d_ws;
  __bf16* k_ws  = q_ws + SZ;
  __bf16* vT_ws = k_ws + SZ;
  // ws use: 6 MB

  proj_kernel<<<dim3(TB * TT / 16), dim3(256), 0, stream>>>(
      x, Wk, Wq, Wv, q_ws, k_ws, vT_ws);
  attn_mfma<<<dim3(TB * (TT / 32)), dim3(256), 0, stream>>>(
      q_ws, k_ws, vT_ws, outp);
}

// Round 5
// 221.527 us; speedup vs baseline: 3.8881x; 1.8097x over previous
//
#include <hip/hip_runtime.h>

// Head: out = dropout(Q K^T / 8, p=0.2) V  (no softmax). B=4 T=4096 E=1024 H=64.
// Round 4: projection moved to bf16 MFMA (WT pre-transposed); attention
// regridded to 1024 blocks (4 KV quarters/block) for VALU-issue occupancy.

#define TB 4
#define TT 4096
#define TE 1024
#define TH 64
#define COMB_SCALE 0.15625f   // 0.125 * 1.25 folded into Q

typedef __bf16 bf16x8 __attribute__((ext_vector_type(8)));
typedef __bf16 bf16x4 __attribute__((ext_vector_type(4)));
typedef float  f32x4  __attribute__((ext_vector_type(4)));

__device__ __forceinline__ unsigned rotl32(unsigned x, int d) {
  return (x << d) | (x >> (32 - d));
}

// Exact JAX threefry2x32, key (0,42); returns o0 ^ o1 (partitionable scheme).
__device__ __forceinline__ unsigned tf_bits(unsigned j) {
  const unsigned ks1 = 42u;
  const unsigned ks2 = 0x1BD11BDAu ^ 42u;
  unsigned x0 = 0u, x1 = j + ks1;
#define TF_RND(d) { x0 += x1; x1 = rotl32(x1, (d)); x1 ^= x0; }
  TF_RND(13) TF_RND(15) TF_RND(26) TF_RND(6)
  x0 += ks1; x1 += ks2 + 1u;
  TF_RND(17) TF_RND(29) TF_RND(16) TF_RND(24)
  x0 += ks2; x1 += 0u + 2u;
  TF_RND(13) TF_RND(15) TF_RND(26) TF_RND(6)
  x0 += 0u;  x1 += ks1 + 3u;
  TF_RND(17) TF_RND(29) TF_RND(16) TF_RND(24)
  x0 += ks1; x1 += ks2 + 4u;
  TF_RND(13) TF_RND(15) TF_RND(26) TF_RND(6)
  x0 += ks2; x1 += 0u + 5u;
#undef TF_RND
  return x0 ^ x1;
}

// keep  <=>  uniform(bits) < 0.8f  <=>  (bits>>9) < 6710887  (exact)
__device__ __forceinline__ bool tf_keep(unsigned j) {
  return (tf_bits(j) >> 9) < 6710887u;
}

// ---------------------------------------------------------------------------
// prep: WT bf16 [192][1024];  rows 0..63 <- Wq^T, 64..127 <- Wk^T, 128..191 <- Wv^T
// ---------------------------------------------------------------------------
__global__ __launch_bounds__(256)
void prep_wt(const float* __restrict__ Wq, const float* __restrict__ Wk,
             const float* __restrict__ Wv, __bf16* __restrict__ WT)
{
  __shared__ float lds[64][65];
  const int wi = blockIdx.x >> 4;          // 0=q 1=k 2=v
  const int k0 = (blockIdx.x & 15) * 64;
  const float* W = (wi == 0) ? Wq : ((wi == 1) ? Wk : Wv);
  const int tid = threadIdx.x;
#pragma unroll
  for (int it = 0; it < 16; ++it) {
    const int idx = tid + it * 256;
    lds[idx >> 6][idx & 63] = W[(size_t)(k0 + (idx >> 6)) * TH + (idx & 63)];
  }
  __syncthreads();
#pragma unroll
  for (int it = 0; it < 16; ++it) {
    const int idx = tid + it * 256;
    const int n = idx >> 6, kk = idx & 63;
    WT[(size_t)(wi * TH + n) * TE + k0 + kk] = (__bf16)lds[kk][n];
  }
}

// ---------------------------------------------------------------------------
// proj via MFMA: out[row][n] = sum_k x[row][k] * WT[n][k], n in [0,192).
// Grid 512; block = 32 rows x 192 cols; wave = 16 rows x 96 cols.
// Epilogue: n<64 -> qs (pre-scaled), <128 -> ks, else vT[b][h][t] (bf16x4).
// ---------------------------------------------------------------------------
__global__ __launch_bounds__(256)
void proj_mfma(const float* __restrict__ x, const __bf16* __restrict__ WT,
               __bf16* __restrict__ qs, __bf16* __restrict__ ks,
               __bf16* __restrict__ vT)
{
  const int tid = threadIdx.x;
  const int w  = tid >> 6, l = tid & 63;
  const int l4 = l >> 4,  lm = l & 15;
  const int rh = w >> 1,  ch = w & 1;
  const int R  = blockIdx.x * 32 + rh * 16;     // wave's 16 rows

  const float*  xr = x  + (size_t)(R + lm) * TE;
  const __bf16* wt = WT + (size_t)(ch * 96 + lm) * TE;

  f32x4 acc[6];
#pragma unroll
  for (int t = 0; t < 6; ++t) acc[t] = (f32x4){0.f, 0.f, 0.f, 0.f};

  for (int k0 = 0; k0 < TE; k0 += 32) {
    const float4 u0 = *reinterpret_cast<const float4*>(xr + k0 + l4 * 8);
    const float4 u1 = *reinterpret_cast<const float4*>(xr + k0 + l4 * 8 + 4);
    bf16x8 am;
    am[0] = (__bf16)u0.x; am[1] = (__bf16)u0.y;
    am[2] = (__bf16)u0.z; am[3] = (__bf16)u0.w;
    am[4] = (__bf16)u1.x; am[5] = (__bf16)u1.y;
    am[6] = (__bf16)u1.z; am[7] = (__bf16)u1.w;
    bf16x8 bn[6];
#pragma unroll
    for (int t = 0; t < 6; ++t)
      bn[t] = *reinterpret_cast<const bf16x8*>(wt + (size_t)t * 16 * TE + k0 + l4 * 8);
#pragma unroll
    for (int t = 0; t < 6; ++t)
      acc[t] = __builtin_amdgcn_mfma_f32_16x16x32_bf16(am, bn[t], acc[t], 0, 0, 0);
  }

  const int row0 = R + l4 * 4;
#pragma unroll
  for (int t = 0; t < 6; ++t) {
    const int n = ch * 96 + t * 16 + lm;
    if (n < TH) {
#pragma unroll
      for (int r = 0; r < 4; ++r)
        qs[(size_t)(row0 + r) * TH + n] = (__bf16)(acc[t][r] * COMB_SCALE);
    } else if (n < 2 * TH) {
#pragma unroll
      for (int r = 0; r < 4; ++r)
        ks[(size_t)(row0 + r) * TH + (n - TH)] = (__bf16)acc[t][r];
    } else {
      bf16x4 vv;
#pragma unroll
      for (int r = 0; r < 4; ++r) vv[r] = (__bf16)acc[t][r];
      const int bb = row0 >> 12, trow = row0 & (TT - 1);
      *reinterpret_cast<bf16x4*>(
          vT + ((size_t)(bb * TH + (n - 2 * TH)) * TT + trow)) = vv;
    }
  }
}

// ---------------------------------------------------------------------------
// Attention, MFMA. Grid 1024: block -> (b, 16 q-rows). 4 waves = 4 KV
// quarters. Barrier-free k-loop; one final barrier for the reduction.
// ---------------------------------------------------------------------------
__global__ __launch_bounds__(256)
void attn_mfma(const __bf16* __restrict__ qs,
               const __bf16* __restrict__ ks,
               const __bf16* __restrict__ vT,
               float* __restrict__ out)
{
  __shared__ __bf16 S_lds[4][16 * 64];   // wave-private, XOR-swizzled
  __shared__ float  Oex[3][16][TH + 1];  // KV-quarter exchange

  const int tid = threadIdx.x;
  const int w   = tid >> 6;
  const int l   = tid & 63;
  const int l4  = l >> 4;     // 0..3
  const int lm  = l & 15;     // 0..15

  const int b     = blockIdx.x >> 8;
  const int qt16  = blockIdx.x & 255;
  const int qrow0 = qt16 * 16;
  const int kv0   = w * (TT / 4);

  const __bf16* qb = qs + ((size_t)b * TT + qrow0) * TH;
  const bf16x8 qf0 = *reinterpret_cast<const bf16x8*>(qb + (size_t)lm * TH + l4 * 8);
  const bf16x8 qf1 = *reinterpret_cast<const bf16x8*>(qb + (size_t)lm * TH + 32 + l4 * 8);

  const __bf16* kbp = ks + (size_t)b * TT * TH;
  const __bf16* vbp = vT + (size_t)b * TH * TT;

  f32x4 o_acc[4];
#pragma unroll
  for (int t = 0; t < 4; ++t) o_acc[t] = (f32x4){0.f, 0.f, 0.f, 0.f};

  const unsigned base0 = ((unsigned)(b * TT) + (unsigned)qrow0 + (unsigned)(l4 * 4)) * (unsigned)TT;
  const unsigned sw = (unsigned)((lm & 7) << 3);

  for (int kb = kv0; kb < kv0 + TT / 4; kb += 64) {
    // ---- K B-frags from global (L2-resident) ----
    bf16x8 kf[4][2];
#pragma unroll
    for (int t = 0; t < 4; ++t) {
      const __bf16* kr = kbp + (size_t)(kb + t * 16 + lm) * TH;
#pragma unroll
      for (int s = 0; s < 2; ++s)
        kf[t][s] = *reinterpret_cast<const bf16x8*>(kr + s * 32 + l4 * 8);
    }

    // ---- S = Q K^T (scale pre-folded into Q) ----
    f32x4 sa[4];
#pragma unroll
    for (int t = 0; t < 4; ++t) {
      f32x4 c = {0.f, 0.f, 0.f, 0.f};
      c = __builtin_amdgcn_mfma_f32_16x16x32_bf16(qf0, kf[t][0], c, 0, 0, 0);
      c = __builtin_amdgcn_mfma_f32_16x16x32_bf16(qf1, kf[t][1], c, 0, 0, 0);
      sa[t] = c;
    }

    // ---- V B-frags (loaded after QK to trim liveness) ----
    bf16x8 vf[4][2];
#pragma unroll
    for (int t = 0; t < 4; ++t) {
      const __bf16* vr = vbp + (size_t)(t * 16 + lm) * TT + kb;
#pragma unroll
      for (int s = 0; s < 2; ++s)
        vf[t][s] = *reinterpret_cast<const bf16x8*>(vr + s * 32 + l4 * 8);
    }

    // ---- dropout mask (threefry, exact) + bf16 + swizzled S store ----
    const unsigned jcol = (unsigned)kb + (unsigned)lm;
#pragma unroll
    for (int t = 0; t < 4; ++t) {
#pragma unroll
      for (int r = 0; r < 4; ++r) {
        const unsigned j = base0 + (unsigned)(r * TT) + jcol + (unsigned)(t * 16);
        const float svv = tf_keep(j) ? sa[t][r] : 0.0f;
        const int row = l4 * 4 + r;
        const int col = t * 16 + lm;
        S_lds[w][row * 64 + (col ^ ((row & 7) << 3))] = (__bf16)svv;
      }
    }

    // ---- reload S as PV A-frags (same-wave dep; compiler inserts lgkmcnt) ----
    const bf16x8 af0 = *reinterpret_cast<const bf16x8*>(
        &S_lds[w][lm * 64 + ((unsigned)(l4 * 8) ^ sw)]);
    const bf16x8 af1 = *reinterpret_cast<const bf16x8*>(
        &S_lds[w][lm * 64 + ((unsigned)(32 + l4 * 8) ^ sw)]);

    // ---- O += S V ----
#pragma unroll
    for (int t = 0; t < 4; ++t) {
      o_acc[t] = __builtin_amdgcn_mfma_f32_16x16x32_bf16(af0, vf[t][0], o_acc[t], 0, 0, 0);
      o_acc[t] = __builtin_amdgcn_mfma_f32_16x16x32_bf16(af1, vf[t][1], o_acc[t], 0, 0, 0);
    }
  }

  // ---- combine KV quarters ----
  if (w > 0) {
#pragma unroll
    for (int t = 0; t < 4; ++t)
#pragma unroll
      for (int r = 0; r < 4; ++r)
        Oex[w - 1][l4 * 4 + r][t * 16 + lm] = o_acc[t][r];
  }
  __syncthreads();
  if (w == 0) {
    float* outb = out + ((size_t)b * TT + qrow0) * TH;
#pragma unroll
    for (int t = 0; t < 4; ++t)
#pragma unroll
      for (int r = 0; r < 4; ++r) {
        const int row = l4 * 4 + r, col = t * 16 + lm;
        const float v = o_acc[t][r] + Oex[0][row][col] + Oex[1][row][col] +
                        Oex[2][row][col];
        outb[(size_t)row * TH + col] = v;
      }
  }
}

extern "C" void kernel_launch(void* const* d_in, const int* in_sizes, int n_in,
                              void* d_out, int out_size, void* d_ws, size_t ws_size,
                              hipStream_t stream) {
  const float* x  = (const float*)d_in[0];
  const float* Wk = (const float*)d_in[1];
  const float* Wq = (const float*)d_in[2];
  const float* Wv = (const float*)d_in[3];
  float* outp = (float*)d_out;

  const size_t SZ = (size_t)TB * TT * TH;  // 1,048,576 elements each
  __bf16* q_ws  = (__bf16*)d_ws;
  __bf16* k_ws  = q_ws + SZ;
  __bf16* vT_ws = k_ws + SZ;
  __bf16* WT_ws = vT_ws + SZ;
  // ws use: 6 MB + 384 KB

  prep_wt<<<dim3(48), dim3(256), 0, stream>>>(Wq, Wk, Wv, WT_ws);
  proj_mfma<<<dim3(TB * TT / 32), dim3(256), 0, stream>>>(
      x, WT_ws, q_ws, k_ws, vT_ws);
  attn_mfma<<<dim3(TB * (TT / 16)), dim3(256), 0, stream>>>(
      q_ws, k_ws, vT_ws, outp);
}

// Round 6
// 219.656 us; speedup vs baseline: 3.9212x; 1.0085x over previous
//
#include <hip/hip_runtime.h>

// Head: out = dropout(Q K^T / 8, p=0.2) V  (no softmax). B=4 T=4096 E=1024 H=64.
// Round 5: (1) threefry rotates forced to v_alignbit_b32 via
// __builtin_amdgcn_alignbit (compiler was emitting 3-op shift/or rotates:
// measured 2300 instr/wave-k-step vs 1400 predicted fused);
// (2) attn occupancy 50%->100% cap: 512-thr blocks, 8 waves = 8 KV-eighths,
// staged LDS tree reduction.

#define TB 4
#define TT 4096
#define TE 1024
#define TH 64
#define COMB_SCALE 0.15625f   // 0.125 * 1.25 folded into Q

typedef __bf16 bf16x8 __attribute__((ext_vector_type(8)));
typedef __bf16 bf16x4 __attribute__((ext_vector_type(4)));
typedef float  f32x4  __attribute__((ext_vector_type(4)));

// single-instruction rotate: v_alignbit_b32(x,x,32-d) == rotl(x,d)
#define ROTL(x, d) __builtin_amdgcn_alignbit((x), (x), 32u - (d))

// Exact JAX threefry2x32, key (0,42); returns o0 ^ o1 (partitionable scheme).
__device__ __forceinline__ unsigned tf_bits(unsigned j) {
  const unsigned ks1 = 42u;
  const unsigned ks2 = 0x1BD11BDAu ^ 42u;
  unsigned x0 = 0u, x1 = j + ks1;
#define TF_RND(d) { x0 += x1; x1 = ROTL(x1, (d)); x1 ^= x0; }
  TF_RND(13u) TF_RND(15u) TF_RND(26u) TF_RND(6u)
  x0 += ks1; x1 += ks2 + 1u;
  TF_RND(17u) TF_RND(29u) TF_RND(16u) TF_RND(24u)
  x0 += ks2; x1 += 0u + 2u;
  TF_RND(13u) TF_RND(15u) TF_RND(26u) TF_RND(6u)
  x0 += 0u;  x1 += ks1 + 3u;
  TF_RND(17u) TF_RND(29u) TF_RND(16u) TF_RND(24u)
  x0 += ks1; x1 += ks2 + 4u;
  TF_RND(13u) TF_RND(15u) TF_RND(26u) TF_RND(6u)
  x0 += ks2; x1 += 0u + 5u;
#undef TF_RND
  return x0 ^ x1;
}

// keep <=> uniform(bits) < 0.8f <=> (bits>>9) < 6710887 <=> bits < 6710887<<9
__device__ __forceinline__ bool tf_keep(unsigned j) {
  return tf_bits(j) < 3435974144u;
}

// ---------------------------------------------------------------------------
// prep: WT bf16 [192][1024];  rows 0..63 <- Wq^T, 64..127 <- Wk^T, 128..191 <- Wv^T
// ---------------------------------------------------------------------------
__global__ __launch_bounds__(256)
void prep_wt(const float* __restrict__ Wq, const float* __restrict__ Wk,
             const float* __restrict__ Wv, __bf16* __restrict__ WT)
{
  __shared__ float lds[64][65];
  const int wi = blockIdx.x >> 4;          // 0=q 1=k 2=v
  const int k0 = (blockIdx.x & 15) * 64;
  const float* W = (wi == 0) ? Wq : ((wi == 1) ? Wk : Wv);
  const int tid = threadIdx.x;
#pragma unroll
  for (int it = 0; it < 16; ++it) {
    const int idx = tid + it * 256;
    lds[idx >> 6][idx & 63] = W[(size_t)(k0 + (idx >> 6)) * TH + (idx & 63)];
  }
  __syncthreads();
#pragma unroll
  for (int it = 0; it < 16; ++it) {
    const int idx = tid + it * 256;
    const int n = idx >> 6, kk = idx & 63;
    WT[(size_t)(wi * TH + n) * TE + k0 + kk] = (__bf16)lds[kk][n];
  }
}

// ---------------------------------------------------------------------------
// proj via MFMA: out[row][n] = sum_k x[row][k] * WT[n][k], n in [0,192).
// Grid 512; block = 32 rows x 192 cols; wave = 16 rows x 96 cols.
// ---------------------------------------------------------------------------
__global__ __launch_bounds__(256)
void proj_mfma(const float* __restrict__ x, const __bf16* __restrict__ WT,
               __bf16* __restrict__ qs, __bf16* __restrict__ ks,
               __bf16* __restrict__ vT)
{
  const int tid = threadIdx.x;
  const int w  = tid >> 6, l = tid & 63;
  const int l4 = l >> 4,  lm = l & 15;
  const int rh = w >> 1,  ch = w & 1;
  const int R  = blockIdx.x * 32 + rh * 16;

  const float*  xr = x  + (size_t)(R + lm) * TE;
  const __bf16* wt = WT + (size_t)(ch * 96 + lm) * TE;

  f32x4 acc[6];
#pragma unroll
  for (int t = 0; t < 6; ++t) acc[t] = (f32x4){0.f, 0.f, 0.f, 0.f};

  for (int k0 = 0; k0 < TE; k0 += 32) {
    const float4 u0 = *reinterpret_cast<const float4*>(xr + k0 + l4 * 8);
    const float4 u1 = *reinterpret_cast<const float4*>(xr + k0 + l4 * 8 + 4);
    bf16x8 am;
    am[0] = (__bf16)u0.x; am[1] = (__bf16)u0.y;
    am[2] = (__bf16)u0.z; am[3] = (__bf16)u0.w;
    am[4] = (__bf16)u1.x; am[5] = (__bf16)u1.y;
    am[6] = (__bf16)u1.z; am[7] = (__bf16)u1.w;
    bf16x8 bn[6];
#pragma unroll
    for (int t = 0; t < 6; ++t)
      bn[t] = *reinterpret_cast<const bf16x8*>(wt + (size_t)t * 16 * TE + k0 + l4 * 8);
#pragma unroll
    for (int t = 0; t < 6; ++t)
      acc[t] = __builtin_amdgcn_mfma_f32_16x16x32_bf16(am, bn[t], acc[t], 0, 0, 0);
  }

  const int row0 = R + l4 * 4;
#pragma unroll
  for (int t = 0; t < 6; ++t) {
    const int n = ch * 96 + t * 16 + lm;
    if (n < TH) {
#pragma unroll
      for (int r = 0; r < 4; ++r)
        qs[(size_t)(row0 + r) * TH + n] = (__bf16)(acc[t][r] * COMB_SCALE);
    } else if (n < 2 * TH) {
#pragma unroll
      for (int r = 0; r < 4; ++r)
        ks[(size_t)(row0 + r) * TH + (n - TH)] = (__bf16)acc[t][r];
    } else {
      bf16x4 vv;
#pragma unroll
      for (int r = 0; r < 4; ++r) vv[r] = (__bf16)acc[t][r];
      const int bb = row0 >> 12, trow = row0 & (TT - 1);
      *reinterpret_cast<bf16x4*>(
          vT + ((size_t)(bb * TH + (n - 2 * TH)) * TT + trow)) = vv;
    }
  }
}

// ---------------------------------------------------------------------------
// Attention, MFMA. Grid 1024 x 512 thr: block -> (b, 16 q-rows); 8 waves =
// 8 KV-eighths (8 k-steps of 64 keys). Barrier-free k-loop; staged LDS tree
// reduction 8->4->2->1 at the end.
// ---------------------------------------------------------------------------
__global__ __launch_bounds__(512, 8)
void attn_mfma(const __bf16* __restrict__ qs,
               const __bf16* __restrict__ ks,
               const __bf16* __restrict__ vT,
               float* __restrict__ out)
{
  __shared__ __bf16 S_lds[8][16 * 64];   // wave-private, XOR-swizzled
  __shared__ float  Oex[4][16][TH + 4];  // reduction exchange

  const int tid = threadIdx.x;
  const int w   = tid >> 6;   // 0..7
  const int l   = tid & 63;
  const int l4  = l >> 4;     // 0..3
  const int lm  = l & 15;     // 0..15

  const int b     = blockIdx.x >> 8;
  const int qt16  = blockIdx.x & 255;
  const int qrow0 = qt16 * 16;
  const int kv0   = w * (TT / 8);

  const __bf16* qb = qs + ((size_t)b * TT + qrow0) * TH;
  const bf16x8 qf0 = *reinterpret_cast<const bf16x8*>(qb + (size_t)lm * TH + l4 * 8);
  const bf16x8 qf1 = *reinterpret_cast<const bf16x8*>(qb + (size_t)lm * TH + 32 + l4 * 8);

  const __bf16* kbp = ks + (size_t)b * TT * TH;
  const __bf16* vbp = vT + (size_t)b * TH * TT;

  f32x4 o_acc[4];
#pragma unroll
  for (int t = 0; t < 4; ++t) o_acc[t] = (f32x4){0.f, 0.f, 0.f, 0.f};

  const unsigned base0 = ((unsigned)(b * TT) + (unsigned)qrow0 + (unsigned)(l4 * 4)) * (unsigned)TT;
  const unsigned sw = (unsigned)((lm & 7) << 3);

  for (int kb = kv0; kb < kv0 + TT / 8; kb += 64) {
    // ---- K B-frags from global (L2-resident) ----
    bf16x8 kf[4][2];
#pragma unroll
    for (int t = 0; t < 4; ++t) {
      const __bf16* kr = kbp + (size_t)(kb + t * 16 + lm) * TH;
#pragma unroll
      for (int s = 0; s < 2; ++s)
        kf[t][s] = *reinterpret_cast<const bf16x8*>(kr + s * 32 + l4 * 8);
    }

    // ---- S = Q K^T (scale pre-folded into Q) ----
    f32x4 sa[4];
#pragma unroll
    for (int t = 0; t < 4; ++t) {
      f32x4 c = {0.f, 0.f, 0.f, 0.f};
      c = __builtin_amdgcn_mfma_f32_16x16x32_bf16(qf0, kf[t][0], c, 0, 0, 0);
      c = __builtin_amdgcn_mfma_f32_16x16x32_bf16(qf1, kf[t][1], c, 0, 0, 0);
      sa[t] = c;
    }

    // ---- V B-frags (loaded after QK to trim liveness) ----
    bf16x8 vf[4][2];
#pragma unroll
    for (int t = 0; t < 4; ++t) {
      const __bf16* vr = vbp + (size_t)(t * 16 + lm) * TT + kb;
#pragma unroll
      for (int s = 0; s < 2; ++s)
        vf[t][s] = *reinterpret_cast<const bf16x8*>(vr + s * 32 + l4 * 8);
    }

    // ---- dropout mask (threefry, exact) + bf16 + swizzled S store ----
    const unsigned jcol = (unsigned)kb + (unsigned)lm;
#pragma unroll
    for (int t = 0; t < 4; ++t) {
#pragma unroll
      for (int r = 0; r < 4; ++r) {
        const unsigned j = base0 + (unsigned)(r * TT) + jcol + (unsigned)(t * 16);
        const float svv = tf_keep(j) ? sa[t][r] : 0.0f;
        const int row = l4 * 4 + r;
        const int col = t * 16 + lm;
        S_lds[w][row * 64 + (col ^ ((row & 7) << 3))] = (__bf16)svv;
      }
    }

    // ---- reload S as PV A-frags (same-wave dep; compiler inserts lgkmcnt) ----
    const bf16x8 af0 = *reinterpret_cast<const bf16x8*>(
        &S_lds[w][lm * 64 + ((unsigned)(l4 * 8) ^ sw)]);
    const bf16x8 af1 = *reinterpret_cast<const bf16x8*>(
        &S_lds[w][lm * 64 + ((unsigned)(32 + l4 * 8) ^ sw)]);

    // ---- O += S V ----
#pragma unroll
    for (int t = 0; t < 4; ++t) {
      o_acc[t] = __builtin_amdgcn_mfma_f32_16x16x32_bf16(af0, vf[t][0], o_acc[t], 0, 0, 0);
      o_acc[t] = __builtin_amdgcn_mfma_f32_16x16x32_bf16(af1, vf[t][1], o_acc[t], 0, 0, 0);
    }
  }

  // ---- staged reduction: 8 -> 4 -> 2 -> 1 ----
  if (w >= 4) {
#pragma unroll
    for (int t = 0; t < 4; ++t)
#pragma unroll
      for (int r = 0; r < 4; ++r)
        Oex[w - 4][l4 * 4 + r][t * 16 + lm] = o_acc[t][r];
  }
  __syncthreads();
  if (w < 4) {
#pragma unroll
    for (int t = 0; t < 4; ++t)
#pragma unroll
      for (int r = 0; r < 4; ++r)
        o_acc[t][r] += Oex[w][l4 * 4 + r][t * 16 + lm];
  }
  __syncthreads();
  if (w == 2 || w == 3) {
#pragma unroll
    for (int t = 0; t < 4; ++t)
#pragma unroll
      for (int r = 0; r < 4; ++r)
        Oex[w - 2][l4 * 4 + r][t * 16 + lm] = o_acc[t][r];
  }
  __syncthreads();
  if (w < 2) {
#pragma unroll
    for (int t = 0; t < 4; ++t)
#pragma unroll
      for (int r = 0; r < 4; ++r)
        o_acc[t][r] += Oex[w][l4 * 4 + r][t * 16 + lm];
  }
  __syncthreads();
  if (w == 1) {
#pragma unroll
    for (int t = 0; t < 4; ++t)
#pragma unroll
      for (int r = 0; r < 4; ++r)
        Oex[0][l4 * 4 + r][t * 16 + lm] = o_acc[t][r];
  }
  __syncthreads();
  if (w == 0) {
    float* outb = out + ((size_t)b * TT + qrow0) * TH;
#pragma unroll
    for (int t = 0; t < 4; ++t)
#pragma unroll
      for (int r = 0; r < 4; ++r) {
        const int row = l4 * 4 + r, col = t * 16 + lm;
        outb[(size_t)row * TH + col] = o_acc[t][r] + Oex[0][row][col];
      }
  }
}

extern "C" void kernel_launch(void* const* d_in, const int* in_sizes, int n_in,
                              void* d_out, int out_size, void* d_ws, size_t ws_size,
                              hipStream_t stream) {
  const float* x  = (const float*)d_in[0];
  const float* Wk = (const float*)d_in[1];
  const float* Wq = (const float*)d_in[2];
  const float* Wv = (const float*)d_in[3];
  float* outp = (float*)d_out;

  const size_t SZ = (size_t)TB * TT * TH;  // 1,048,576 elements each
  __bf16* q_ws  = (__bf16*)d_ws;
  __bf16* k_ws  = q_ws + SZ;
  __bf16* vT_ws = k_ws + SZ;
  __bf16* WT_ws = vT_ws + SZ;
  // ws use: 6 MB + 384 KB

  prep_wt<<<dim3(48), dim3(256), 0, stream>>>(Wq, Wk, Wv, WT_ws);
  proj_mfma<<<dim3(TB * TT / 32), dim3(256), 0, stream>>>(
      x, WT_ws, q_ws, k_ws, vT_ws);
  attn_mfma<<<dim3(TB * (TT / 16)), dim3(512), 0, stream>>>(
      q_ws, k_ws, vT_ws, outp);
}